// Round 1
// baseline (632.108 us; speedup 1.0000x reference)
//
#include <hip/hip_runtime.h>
#include <hip/hip_bf16.h>

#define TIN 96
#define TDEC 128

__device__ __forceinline__ float sigm(float x) {
    return __builtin_amdgcn_rcpf(1.0f + __expf(-x));
}
__device__ __forceinline__ float tanh_(float x) {
    float e = __expf(2.0f * x);
    return 1.0f - 2.0f * __builtin_amdgcn_rcpf(e + 1.0f);
}

__global__ __launch_bounds__(256, 4) void fused_vdencdec(
    const float* __restrict__ x,
    const float* __restrict__ e1_Wih, const float* __restrict__ e1_Whh, const float* __restrict__ e1_b,
    const float* __restrict__ e2_Wih, const float* __restrict__ e2_Whh, const float* __restrict__ e2_b,
    const float* __restrict__ d1_Wih, const float* __restrict__ d1_Whh, const float* __restrict__ d1_b,
    const float* __restrict__ d2_Wih, const float* __restrict__ d2_Whh, const float* __restrict__ d2_b,
    const float* __restrict__ fc1_W, const float* __restrict__ fc1_b,
    const float* __restrict__ fc2_W, const float* __restrict__ fc2_b,
    float* __restrict__ out)
{
    __shared__ float x_s[TIN * 8];       // 768
    __shared__ float h1_all[TIN * 64];   // 6144; reused for d1h/pd2/flat/mid after e2
    __shared__ float pre_s[256];
    __shared__ float pe2[TIN * 4];       // 384
    __shared__ float dec_in_s[TDEC];     // 128
    __shared__ float wih2_s[256];        // e2_Wih staged

    const int t = threadIdx.x;
    const int b = blockIdx.x;

    // aliases into h1_all, valid only after the e2-xg phase is done with h1_all
    float* d1h    = h1_all;          // 128*16 = 2048
    float* pd2    = h1_all + 2048;   // 512
    float* flat_s = h1_all + 2560;   // 128
    float* mid_s  = h1_all + 2688;   // 32

    // ---- stage x[b] and e2_Wih into LDS ----
    const float* xb = x + (size_t)b * (TIN * 8);
    for (int i = t; i < TIN * 8; i += 256) x_s[i] = xb[i];
    wih2_s[t] = e2_Wih[t];

    // ---- per-thread e1 weights in registers ----
    float wih[8];
    #pragma unroll
    for (int i = 0; i < 8; ++i) wih[i] = e1_Wih[t * 8 + i];
    float whh[64];
    {
        const float4* wp = (const float4*)(e1_Whh + t * 64);
        #pragma unroll
        for (int q = 0; q < 16; ++q) {
            float4 w4 = wp[q];
            whh[4*q+0] = w4.x; whh[4*q+1] = w4.y; whh[4*q+2] = w4.z; whh[4*q+3] = w4.w;
        }
    }
    const float bias = e1_b[t];
    float c1 = 0.0f;  // cell state, used by threads t<64 only

    __syncthreads();

    // =================== e1: LSTM(8 -> 64), 96 steps ===================
    for (int ts = 0; ts < TIN; ++ts) {
        float a0 = bias, a1 = 0.f, a2 = 0.f, a3 = 0.f;
        {
            const float4* xp = (const float4*)&x_s[ts * 8];
            float4 xv0 = xp[0], xv1 = xp[1];
            a0 = fmaf(xv0.x, wih[0], a0); a1 = fmaf(xv0.y, wih[1], a1);
            a2 = fmaf(xv0.z, wih[2], a2); a3 = fmaf(xv0.w, wih[3], a3);
            a0 = fmaf(xv1.x, wih[4], a0); a1 = fmaf(xv1.y, wih[5], a1);
            a2 = fmaf(xv1.z, wih[6], a2); a3 = fmaf(xv1.w, wih[7], a3);
        }
        if (ts > 0) {
            const float4* hp = (const float4*)&h1_all[(ts - 1) * 64];
            #pragma unroll
            for (int q = 0; q < 16; ++q) {
                float4 hv = hp[q];
                a0 = fmaf(hv.x, whh[4*q+0], a0);
                a1 = fmaf(hv.y, whh[4*q+1], a1);
                a2 = fmaf(hv.z, whh[4*q+2], a2);
                a3 = fmaf(hv.w, whh[4*q+3], a3);
            }
        }
        pre_s[t] = (a0 + a1) + (a2 + a3);
        __syncthreads();
        if (t < 64) {
            float pi = pre_s[t], pf = pre_s[64 + t], pg = pre_s[128 + t], po = pre_s[192 + t];
            c1 = sigm(pf) * c1 + sigm(pi) * tanh_(pg);
            h1_all[ts * 64 + t] = sigm(po) * tanh_(c1);
        }
        __syncthreads();
    }

    // =================== e2 xg: pe2[ts*4+g] = e2_b[g] + h1[ts] . e2_Wih[g] ===================
    for (int o = t; o < TIN * 4; o += 256) {
        int ts = o >> 2, g = o & 3;
        const float* hr = &h1_all[ts * 64];
        const float* wr = &wih2_s[g * 64];
        float a0 = 0.f, a1 = 0.f, a2 = 0.f, a3 = 0.f;
        #pragma unroll 8
        for (int k = 0; k < 64; k += 4) {
            a0 = fmaf(hr[k+0], wr[k+0], a0);
            a1 = fmaf(hr[k+1], wr[k+1], a1);
            a2 = fmaf(hr[k+2], wr[k+2], a2);
            a3 = fmaf(hr[k+3], wr[k+3], a3);
        }
        pe2[o] = (a0 + a1) + (a2 + a3) + e2_b[g];
    }
    __syncthreads();

    // =================== e2 recurrence (H=1) + relu, build dec_in ===================
    if (t == 0) {
        float w0 = e2_Whh[0], w1 = e2_Whh[1], w2 = e2_Whh[2], w3 = e2_Whh[3];
        float h = 0.f, c = 0.f;
        for (int ts = 0; ts < TIN; ++ts) {
            float gi = pe2[ts*4+0] + h * w0;
            float gf = pe2[ts*4+1] + h * w1;
            float gg = pe2[ts*4+2] + h * w2;
            float go = pe2[ts*4+3] + h * w3;
            c = sigm(gf) * c + sigm(gi) * tanh_(gg);
            h = sigm(go) * tanh_(c);
            dec_in_s[ts] = fmaxf(h, 0.f);
        }
    }
    if (t < 32) dec_in_s[TIN + t] = x_s[(64 + t) * 8];  // x_aux = x[:, -32:, 0]
    __syncthreads();

    // =================== decoder: wave 0 only, wave-synchronous ===================
    if (t < 64) {
        const int u = t & 15;
        // ---- d1: LSTM(1 -> 16), 128 steps; lane = gate-unit ----
        float wih1 = d1_Wih[t];
        float b1   = d1_b[t];
        float whh1[16];
        {
            const float4* wp = (const float4*)(d1_Whh + t * 16);
            #pragma unroll
            for (int q = 0; q < 4; ++q) {
                float4 w4 = wp[q];
                whh1[4*q+0] = w4.x; whh1[4*q+1] = w4.y; whh1[4*q+2] = w4.z; whh1[4*q+3] = w4.w;
            }
        }
        float c = 0.f;
        for (int ts = 0; ts < TDEC; ++ts) {
            float a = fmaf(dec_in_s[ts], wih1, b1);
            if (ts > 0) {
                const float4* hp = (const float4*)&d1h[(ts - 1) * 16];
                #pragma unroll
                for (int q = 0; q < 4; ++q) {
                    float4 hv = hp[q];
                    a = fmaf(hv.x, whh1[4*q+0], a);
                    a = fmaf(hv.y, whh1[4*q+1], a);
                    a = fmaf(hv.z, whh1[4*q+2], a);
                    a = fmaf(hv.w, whh1[4*q+3], a);
                }
            }
            float pi = __shfl(a, u);
            float pf = __shfl(a, 16 + u);
            float pg = __shfl(a, 32 + u);
            float po = __shfl(a, 48 + u);
            c = sigm(pf) * c + sigm(pi) * tanh_(pg);
            float h = sigm(po) * tanh_(c);
            if (t < 16) d1h[ts * 16 + t] = h;
        }

        // ---- d2 xg: pd2[ts*4+g] ----
        for (int o = t; o < TDEC * 4; o += 64) {
            int ts2 = o >> 2, g = o & 3;
            const float* hr = &d1h[ts2 * 16];
            const float* wr = d2_Wih + g * 16;
            float a = d2_b[g];
            #pragma unroll
            for (int k = 0; k < 16; ++k) a = fmaf(hr[k], wr[k], a);
            pd2[o] = a;
        }

        // ---- d2 recurrence (H=1) ----
        if (t == 0) {
            float w0 = d2_Whh[0], w1 = d2_Whh[1], w2 = d2_Whh[2], w3 = d2_Whh[3];
            float h = 0.f, c2 = 0.f;
            for (int ts2 = 0; ts2 < TDEC; ++ts2) {
                float gi = pd2[ts2*4+0] + h * w0;
                float gf = pd2[ts2*4+1] + h * w1;
                float gg = pd2[ts2*4+2] + h * w2;
                float go = pd2[ts2*4+3] + h * w3;
                c2 = sigm(gf) * c2 + sigm(gi) * tanh_(gg);
                h = sigm(go) * tanh_(c2);
                flat_s[ts2] = h;
            }
        }

        // ---- fc1 (128 -> 32) + fc2 (32 -> 32) ----
        if (t < 32) {
            float a = fc1_b[t];
            const float* wr = fc1_W + t * 128;
            #pragma unroll 4
            for (int k = 0; k < 128; ++k) a = fmaf(flat_s[k], wr[k], a);
            mid_s[t] = a;
        }
        if (t < 32) {
            float a = fc2_b[t];
            const float* wr = fc2_W + t * 32;
            #pragma unroll
            for (int k = 0; k < 32; ++k) a = fmaf(mid_s[k], wr[k], a);
            out[(size_t)b * 32 + t] = a;
        }
    }
}

extern "C" void kernel_launch(void* const* d_in, const int* in_sizes, int n_in,
                              void* d_out, int out_size, void* d_ws, size_t ws_size,
                              hipStream_t stream) {
    const float* x      = (const float*)d_in[0];
    const float* e1_Wih = (const float*)d_in[1];
    const float* e1_Whh = (const float*)d_in[2];
    const float* e1_b   = (const float*)d_in[3];
    const float* e2_Wih = (const float*)d_in[4];
    const float* e2_Whh = (const float*)d_in[5];
    const float* e2_b   = (const float*)d_in[6];
    const float* d1_Wih = (const float*)d_in[7];
    const float* d1_Whh = (const float*)d_in[8];
    const float* d1_b   = (const float*)d_in[9];
    const float* d2_Wih = (const float*)d_in[10];
    const float* d2_Whh = (const float*)d_in[11];
    const float* d2_b   = (const float*)d_in[12];
    const float* fc1_W  = (const float*)d_in[13];
    const float* fc1_b  = (const float*)d_in[14];
    const float* fc2_W  = (const float*)d_in[15];
    const float* fc2_b  = (const float*)d_in[16];
    float* out = (float*)d_out;

    hipLaunchKernelGGL(fused_vdencdec, dim3(4096), dim3(256), 0, stream,
        x, e1_Wih, e1_Whh, e1_b, e2_Wih, e2_Whh, e2_b,
        d1_Wih, d1_Whh, d1_b, d2_Wih, d2_Whh, d2_b,
        fc1_W, fc1_b, fc2_W, fc2_b, out);
}

// Round 2
// 447.024 us; speedup vs baseline: 1.4140x; 1.4140x over previous
//
#include <hip/hip_runtime.h>
#include <hip/hip_bf16.h>

__device__ __forceinline__ float sigm(float x) {
    return __builtin_amdgcn_rcpf(1.0f + __expf(-x));
}
__device__ __forceinline__ float tanh_(float x) {
    float e = __expf(2.0f * x);
    return 1.0f - 2.0f * __builtin_amdgcn_rcpf(e + 1.0f);
}
__device__ __forceinline__ float rl(float v, int l) {
    return __uint_as_float(__builtin_amdgcn_readlane(__float_as_uint(v), l));
}

// ============ K1: e1 LSTM(8->64) over 96 steps + e2 gate-preacts ============
// 1 batch/block, 128 threads (2 waves). Thread (w, u): wave0 owns gates {i,g}
// of unit u, wave1 owns {f,o}. Whh rows in VGPRs; h lane-distributed, broadcast
// via v_readlane. Cross-wave gate exchange via double-buffered LDS float2.
__global__ __launch_bounds__(128, 2) void k1_e1(
    const float* __restrict__ x,
    const float* __restrict__ e1_Wih, const float* __restrict__ e1_Whh, const float* __restrict__ e1_b,
    const float* __restrict__ e2_Wih, const float* __restrict__ e2_b,
    float* __restrict__ pe2)   // layout [ts][4096][4]
{
    __shared__ float x_s[768];
    __shared__ float h1[96 * 68];      // stride 68 -> 4-bank shift/row
    __shared__ float2 ex[2][2][64];
    __shared__ float wih2_s[4 * 68];

    const int t = threadIdx.x;
    const int w = t >> 6, u = t & 63;
    const int b = blockIdx.x;

    for (int i = t; i < 768; i += 128) x_s[i] = x[(size_t)b * 768 + i];
    for (int i = t; i < 256; i += 128) wih2_s[(i >> 6) * 68 + (i & 63)] = e2_Wih[i];

    const int rowA = w * 64 + u;         // w0: i-gate, w1: f-gate
    const int rowB = 128 + w * 64 + u;   // w0: g-gate, w1: o-gate

    float whhA[64], whhB[64];
    {
        const float4* wa = (const float4*)(e1_Whh + (size_t)rowA * 64);
        const float4* wb = (const float4*)(e1_Whh + (size_t)rowB * 64);
        #pragma unroll
        for (int q = 0; q < 16; ++q) {
            float4 a = wa[q], bq = wb[q];
            whhA[4*q+0] = a.x;  whhA[4*q+1] = a.y;  whhA[4*q+2] = a.z;  whhA[4*q+3] = a.w;
            whhB[4*q+0] = bq.x; whhB[4*q+1] = bq.y; whhB[4*q+2] = bq.z; whhB[4*q+3] = bq.w;
        }
    }
    float wihA[8], wihB[8];
    {
        const float4* wa = (const float4*)(e1_Wih + (size_t)rowA * 8);
        const float4* wb = (const float4*)(e1_Wih + (size_t)rowB * 8);
        float4 a0 = wa[0], a1 = wa[1], b0 = wb[0], b1 = wb[1];
        wihA[0]=a0.x; wihA[1]=a0.y; wihA[2]=a0.z; wihA[3]=a0.w;
        wihA[4]=a1.x; wihA[5]=a1.y; wihA[6]=a1.z; wihA[7]=a1.w;
        wihB[0]=b0.x; wihB[1]=b0.y; wihB[2]=b0.z; wihB[3]=b0.w;
        wihB[4]=b1.x; wihB[5]=b1.y; wihB[6]=b1.z; wihB[7]=b1.w;
    }
    const float bA = e1_b[rowA], bB = e1_b[rowB];

    float h = 0.0f, c = 0.0f;
    __syncthreads();

    for (int ts = 0; ts < 96; ++ts) {
        float aA[4], aB[4];
        aA[0] = bA; aA[1] = 0.f; aA[2] = 0.f; aA[3] = 0.f;
        aB[0] = bB; aB[1] = 0.f; aB[2] = 0.f; aB[3] = 0.f;

        // x-part
        {
            const float4* xp = (const float4*)(x_s + ts * 8);
            float4 x0 = xp[0], x1 = xp[1];
            float xv[8] = {x0.x, x0.y, x0.z, x0.w, x1.x, x1.y, x1.z, x1.w};
            #pragma unroll
            for (int i = 0; i < 8; ++i) {
                aA[i & 3] = fmaf(xv[i], wihA[i], aA[i & 3]);
                aB[i & 3] = fmaf(xv[i], wihB[i], aB[i & 3]);
            }
        }
        // h-part: broadcast lane-distributed h via readlane
        if (ts > 0) {
            #pragma unroll
            for (int k = 0; k < 64; ++k) {
                float hk = rl(h, k);
                aA[k & 3] = fmaf(hk, whhA[k], aA[k & 3]);
                aB[k & 3] = fmaf(hk, whhB[k], aB[k & 3]);
            }
        }
        float pA = (aA[0] + aA[1]) + (aA[2] + aA[3]);
        float pB = (aB[0] + aB[1]) + (aB[2] + aB[3]);

        const int p = ts & 1;
        ex[p][w][u] = make_float2(pA, pB);
        __syncthreads();
        float2 other = ex[p][1 - w][u];

        float pi, pf, pg, po;
        if (w == 0) { pi = pA;      pg = pB;      pf = other.x; po = other.y; }
        else        { pf = pA;      po = pB;      pi = other.x; pg = other.y; }

        float si = sigm(pi), sf = sigm(pf), tg = tanh_(pg), so = sigm(po);
        c = fmaf(sf, c, si * tg);
        h = so * tanh_(c);
        if (w == 0) h1[ts * 68 + u] = h;
    }
    __syncthreads();

    // e2 gate preacts: pe2[ts][b][g] = e2_b[g] + h1[ts] . e2_Wih[g]
    #pragma unroll
    for (int r = 0; r < 3; ++r) {
        int o = r * 128 + t;          // 0..383
        int ts = o >> 2, g = o & 3;
        const float4* hp = (const float4*)(h1 + ts * 68);
        const float4* wp = (const float4*)(wih2_s + g * 68);
        float a0 = 0.f, a1 = 0.f, a2 = 0.f, a3 = 0.f;
        #pragma unroll
        for (int q = 0; q < 16; ++q) {
            float4 hv = hp[q], wv = wp[q];
            a0 = fmaf(hv.x, wv.x, a0); a1 = fmaf(hv.y, wv.y, a1);
            a2 = fmaf(hv.z, wv.z, a2); a3 = fmaf(hv.w, wv.w, a3);
        }
        pe2[((size_t)ts * 4096 + b) * 4 + g] = (a0 + a1) + (a2 + a3) + e2_b[g];
    }
}

// ============ K2: e2 recurrence (H=1), lane = batch; build dec_in ============
__global__ void k2_e2(const float* __restrict__ pe2, const float* __restrict__ e2_Whh,
                      const float* __restrict__ x, float* __restrict__ dec_in)
{
    const int b = blockIdx.x * 256 + threadIdx.x;   // 16 blocks -> 4096 lanes
    const float w0 = e2_Whh[0], w1 = e2_Whh[1], w2 = e2_Whh[2], w3 = e2_Whh[3];
    const float4* pp = (const float4*)pe2;
    float h = 0.f, c = 0.f;
    for (int ts = 0; ts < 96; ++ts) {
        float4 g4 = pp[(size_t)ts * 4096 + b];
        float gi = fmaf(h, w0, g4.x);
        float gf = fmaf(h, w1, g4.y);
        float gg = fmaf(h, w2, g4.z);
        float go = fmaf(h, w3, g4.w);
        c = fmaf(sigm(gf), c, sigm(gi) * tanh_(gg));
        h = sigm(go) * tanh_(c);
        dec_in[(size_t)b * 128 + ts] = fmaxf(h, 0.f);
    }
    #pragma unroll 4
    for (int j = 0; j < 32; ++j)
        dec_in[(size_t)b * 128 + 96 + j] = x[(size_t)b * 768 + (64 + j) * 8];
}

// ============ K3: d1 LSTM(1->16) 128 steps, 4 batches/wave + fused d2-xg ============
// lane = (q = batch-in-wave, u = unit). Each lane owns unit u's 4 gates.
// h[16] per batch round-trips through a wave-private LDS row.
__global__ __launch_bounds__(256, 2) void k3_d1(
    const float* __restrict__ dec_in,
    const float* __restrict__ d1_Wih, const float* __restrict__ d1_Whh, const float* __restrict__ d1_b,
    const float* __restrict__ d2_Wih, const float* __restrict__ d2_b,
    float* __restrict__ pd2)   // layout [ts][4096][4]
{
    __shared__ float din_s[16 * 128];
    __shared__ float h_lds[16][16];

    const int t = threadIdx.x;
    const int w = t >> 6, lane = t & 63;
    const int q = lane >> 4, u = lane & 15;
    const int row = w * 4 + q;                  // batch-in-block 0..15
    const size_t b = (size_t)blockIdx.x * 16 + row;

    for (int i = t; i < 2048; i += 256) din_s[i] = dec_in[(size_t)blockIdx.x * 2048 + i];

    float wih_g[4], bg[4], whh_g[4][16], d2w[16];
    #pragma unroll
    for (int g = 0; g < 4; ++g) {
        wih_g[g] = d1_Wih[g * 16 + u];
        bg[g]    = d1_b[g * 16 + u];
        const float4* wp = (const float4*)(d1_Whh + (size_t)(g * 16 + u) * 16);
        #pragma unroll
        for (int qq = 0; qq < 4; ++qq) {
            float4 v = wp[qq];
            whh_g[g][4*qq+0] = v.x; whh_g[g][4*qq+1] = v.y;
            whh_g[g][4*qq+2] = v.z; whh_g[g][4*qq+3] = v.w;
        }
    }
    {
        const float4* wp = (const float4*)(d2_Wih + (size_t)(u & 3) * 16);
        #pragma unroll
        for (int qq = 0; qq < 4; ++qq) {
            float4 v = wp[qq];
            d2w[4*qq+0] = v.x; d2w[4*qq+1] = v.y; d2w[4*qq+2] = v.z; d2w[4*qq+3] = v.w;
        }
    }
    const float d2bias = d2_b[u & 3];

    float h = 0.f, c = 0.f;
    __syncthreads();

    float hv[16];
    for (int ts = 0; ts < 128; ++ts) {
        float xv = din_s[row * 128 + ts];
        float p0 = fmaf(xv, wih_g[0], bg[0]);
        float p1 = fmaf(xv, wih_g[1], bg[1]);
        float p2 = fmaf(xv, wih_g[2], bg[2]);
        float p3 = fmaf(xv, wih_g[3], bg[3]);
        if (ts > 0) {
            const float4* hp = (const float4*)&h_lds[row][0];
            #pragma unroll
            for (int qq = 0; qq < 4; ++qq) {
                float4 v = hp[qq];
                hv[4*qq+0] = v.x; hv[4*qq+1] = v.y; hv[4*qq+2] = v.z; hv[4*qq+3] = v.w;
            }
            #pragma unroll
            for (int k = 0; k < 16; ++k) {
                p0 = fmaf(hv[k], whh_g[0][k], p0);
                p1 = fmaf(hv[k], whh_g[1][k], p1);
                p2 = fmaf(hv[k], whh_g[2][k], p2);
                p3 = fmaf(hv[k], whh_g[3][k], p3);
            }
            if (u < 4) {   // d2 gate preact for step ts-1
                float a = d2bias;
                #pragma unroll
                for (int k = 0; k < 16; ++k) a = fmaf(hv[k], d2w[k], a);
                pd2[((size_t)(ts - 1) * 4096 + b) * 4 + u] = a;
            }
        }
        c = fmaf(sigm(p1), c, sigm(p0) * tanh_(p2));
        h = sigm(p3) * tanh_(c);
        h_lds[row][u] = h;
    }
    {   // final d2 preact (ts = 127)
        const float4* hp = (const float4*)&h_lds[row][0];
        #pragma unroll
        for (int qq = 0; qq < 4; ++qq) {
            float4 v = hp[qq];
            hv[4*qq+0] = v.x; hv[4*qq+1] = v.y; hv[4*qq+2] = v.z; hv[4*qq+3] = v.w;
        }
        if (u < 4) {
            float a = d2bias;
            #pragma unroll
            for (int k = 0; k < 16; ++k) a = fmaf(hv[k], d2w[k], a);
            pd2[((size_t)127 * 4096 + b) * 4 + u] = a;
        }
    }
}

// ============ K5: d2 recurrence (H=1), lane = batch ============
__global__ void k5_d2(const float* __restrict__ pd2, const float* __restrict__ d2_Whh,
                      float* __restrict__ d2h)   // layout [ts][4096]
{
    const int b = blockIdx.x * 256 + threadIdx.x;
    const float w0 = d2_Whh[0], w1 = d2_Whh[1], w2 = d2_Whh[2], w3 = d2_Whh[3];
    const float4* pp = (const float4*)pd2;
    float h = 0.f, c = 0.f;
    for (int ts = 0; ts < 128; ++ts) {
        float4 g4 = pp[(size_t)ts * 4096 + b];
        float gi = fmaf(h, w0, g4.x);
        float gf = fmaf(h, w1, g4.y);
        float gg = fmaf(h, w2, g4.z);
        float go = fmaf(h, w3, g4.w);
        c = fmaf(sigm(gf), c, sigm(gi) * tanh_(gg));
        h = sigm(go) * tanh_(c);
        d2h[(size_t)ts * 4096 + b] = h;
    }
}

// ============ K6: fc1(128->32) + fc2(32->32), 8 batches/block ============
__global__ __launch_bounds__(256) void k6_fc(
    const float* __restrict__ d2h,
    const float* __restrict__ fc1_W, const float* __restrict__ fc1_b,
    const float* __restrict__ fc2_W, const float* __restrict__ fc2_b,
    float* __restrict__ out)
{
    __shared__ float flat_s[8][128];
    __shared__ float mid_s[8][32];
    const int t = threadIdx.x;
    const int s = t >> 5, o = t & 31;
    const size_t b0 = (size_t)blockIdx.x * 8;

    for (int i = t; i < 1024; i += 256) {
        int ts = i >> 3, ss = i & 7;
        flat_s[ss][ts] = d2h[(size_t)ts * 4096 + b0 + ss];
    }
    __syncthreads();

    float a = fc1_b[o];
    {
        const float4* wp = (const float4*)(fc1_W + (size_t)o * 128);
        const float4* fp = (const float4*)flat_s[s];
        #pragma unroll
        for (int qq = 0; qq < 32; ++qq) {
            float4 f = fp[qq], wv = wp[qq];
            a = fmaf(f.x, wv.x, a); a = fmaf(f.y, wv.y, a);
            a = fmaf(f.z, wv.z, a); a = fmaf(f.w, wv.w, a);
        }
    }
    mid_s[s][o] = a;
    __syncthreads();

    float a2 = fc2_b[o];
    {
        const float4* wp = (const float4*)(fc2_W + (size_t)o * 32);
        const float4* mp = (const float4*)mid_s[s];
        #pragma unroll
        for (int qq = 0; qq < 8; ++qq) {
            float4 m = mp[qq], wv = wp[qq];
            a2 = fmaf(m.x, wv.x, a2); a2 = fmaf(m.y, wv.y, a2);
            a2 = fmaf(m.z, wv.z, a2); a2 = fmaf(m.w, wv.w, a2);
        }
    }
    out[(b0 + s) * 32 + o] = a2;
}

extern "C" void kernel_launch(void* const* d_in, const int* in_sizes, int n_in,
                              void* d_out, int out_size, void* d_ws, size_t ws_size,
                              hipStream_t stream) {
    const float* x      = (const float*)d_in[0];
    const float* e1_Wih = (const float*)d_in[1];
    const float* e1_Whh = (const float*)d_in[2];
    const float* e1_b   = (const float*)d_in[3];
    const float* e2_Wih = (const float*)d_in[4];
    const float* e2_Whh = (const float*)d_in[5];
    const float* e2_b   = (const float*)d_in[6];
    const float* d1_Wih = (const float*)d_in[7];
    const float* d1_Whh = (const float*)d_in[8];
    const float* d1_b   = (const float*)d_in[9];
    const float* d2_Wih = (const float*)d_in[10];
    const float* d2_Whh = (const float*)d_in[11];
    const float* d2_b   = (const float*)d_in[12];
    const float* fc1_W  = (const float*)d_in[13];
    const float* fc1_b  = (const float*)d_in[14];
    const float* fc2_W  = (const float*)d_in[15];
    const float* fc2_b  = (const float*)d_in[16];
    float* out = (float*)d_out;

    float* ws     = (float*)d_ws;
    float* pe2    = ws;                 // [96][4096][4]  (1.57M floats); reused as pd2 [128][4096][4] (2.10M)
    float* dec_in = ws + 2097152;       // [4096][128]    (0.52M floats)
    float* d2h    = ws + 2621440;       // [128][4096]    (0.52M floats)

    hipLaunchKernelGGL(k1_e1, dim3(4096), dim3(128), 0, stream,
                       x, e1_Wih, e1_Whh, e1_b, e2_Wih, e2_b, pe2);
    hipLaunchKernelGGL(k2_e2, dim3(16), dim3(256), 0, stream, pe2, e2_Whh, x, dec_in);
    hipLaunchKernelGGL(k3_d1, dim3(256), dim3(256), 0, stream,
                       dec_in, d1_Wih, d1_Whh, d1_b, d2_Wih, d2_b, pe2 /*pd2*/);
    hipLaunchKernelGGL(k5_d2, dim3(16), dim3(256), 0, stream, pe2 /*pd2*/, d2_Whh, d2h);
    hipLaunchKernelGGL(k6_fc, dim3(512), dim3(256), 0, stream,
                       d2h, fc1_W, fc1_b, fc2_W, fc2_b, out);
}

// Round 3
// 392.539 us; speedup vs baseline: 1.6103x; 1.1388x over previous
//
#include <hip/hip_runtime.h>
#include <hip/hip_bf16.h>

#define NB 4

__device__ __forceinline__ float sigm(float x) {
    return __builtin_amdgcn_rcpf(1.0f + __expf(-x));
}
__device__ __forceinline__ float tanh_(float x) {
    float e = __expf(2.0f * x);
    return 1.0f - 2.0f * __builtin_amdgcn_rcpf(e + 1.0f);
}

// ============ K1: e1 LSTM(8->64) over 96 steps, NB=4 batches/block, fused e2-xg ============
// 256 threads. Phase A: thread t owns gate-row t (whh[64] in VGPRs, asm-pinned)
// for all 4 batches; h broadcast via uniform-address LDS reads. Phase B: thread
// (w=t>>6 -> batch, u=t&63 -> unit) does activations (c in a register) and the
// fused e2 gate-preact via 4 FMA + shfl_xor reduce.
__global__ __launch_bounds__(256, 2) void k1_e1(
    const float* __restrict__ x,
    const float* __restrict__ e1_Wih, const float* __restrict__ e1_Whh, const float* __restrict__ e1_b,
    const float* __restrict__ e2_Wih, const float* __restrict__ e2_b,
    float* __restrict__ pe2)   // [ts][4096][4]
{
    __shared__ float x_s[NB][768];
    __shared__ float pre[NB][256];
    __shared__ float h_s[NB][64];

    const int t = threadIdx.x;
    const int b0 = blockIdx.x * NB;

    // stage x for 4 batches (coalesced)
    #pragma unroll
    for (int nb = 0; nb < NB; ++nb)
        for (int i = t; i < 768; i += 256)
            x_s[nb][i] = x[(size_t)(b0 + nb) * 768 + i];

    // gate-row weights -> VGPRs, pinned against rematerialization
    float whh[64];
    {
        const float4* wp = (const float4*)(e1_Whh + (size_t)t * 64);
        #pragma unroll
        for (int q = 0; q < 16; ++q) {
            float4 w4 = wp[q];
            whh[4*q+0] = w4.x; whh[4*q+1] = w4.y; whh[4*q+2] = w4.z; whh[4*q+3] = w4.w;
        }
        #pragma unroll
        for (int k = 0; k < 64; ++k) asm volatile("" : "+v"(whh[k]));
    }
    float wih[8];
    {
        const float4* wp = (const float4*)(e1_Wih + (size_t)t * 8);
        float4 w0 = wp[0], w1 = wp[1];
        wih[0]=w0.x; wih[1]=w0.y; wih[2]=w0.z; wih[3]=w0.w;
        wih[4]=w1.x; wih[5]=w1.y; wih[6]=w1.z; wih[7]=w1.w;
        #pragma unroll
        for (int k = 0; k < 8; ++k) asm volatile("" : "+v"(wih[k]));
    }
    const float bias = e1_b[t];

    // phase-B statics
    const int w = t >> 6, u = t & 63;
    const int g = u >> 4, part = u & 15;
    float e2w0 = e2_Wih[g * 64 + part * 4 + 0];
    float e2w1 = e2_Wih[g * 64 + part * 4 + 1];
    float e2w2 = e2_Wih[g * 64 + part * 4 + 2];
    float e2w3 = e2_Wih[g * 64 + part * 4 + 3];
    const float e2bias = e2_b[g];
    float c_reg = 0.0f;

    __syncthreads();

    for (int ts = 0; ts < 96; ++ts) {
        // ---------- Phase A: preacts for row t, 4 batches ----------
        float accA[NB], accB[NB];
        #pragma unroll
        for (int nb = 0; nb < NB; ++nb) {
            const float4* xp = (const float4*)&x_s[nb][ts * 8];
            float4 x0 = xp[0], x1 = xp[1];
            float a = bias;
            a = fmaf(x0.x, wih[0], a); a = fmaf(x0.y, wih[1], a);
            a = fmaf(x0.z, wih[2], a); a = fmaf(x0.w, wih[3], a);
            accA[nb] = a;
            float bacc = 0.f;
            bacc = fmaf(x1.x, wih[4], bacc); bacc = fmaf(x1.y, wih[5], bacc);
            bacc = fmaf(x1.z, wih[6], bacc); bacc = fmaf(x1.w, wih[7], bacc);
            accB[nb] = bacc;
        }
        if (ts > 0) {
            #pragma unroll
            for (int kc = 0; kc < 8; ++kc) {
                const int k0 = kc * 8;
                #pragma unroll
                for (int nb = 0; nb < NB; ++nb) {
                    float4 h0 = *(const float4*)&h_s[nb][k0];      // uniform broadcast
                    float4 h1 = *(const float4*)&h_s[nb][k0 + 4];
                    accA[nb] = fmaf(h0.x, whh[k0+0], accA[nb]);
                    accA[nb] = fmaf(h0.y, whh[k0+1], accA[nb]);
                    accA[nb] = fmaf(h0.z, whh[k0+2], accA[nb]);
                    accA[nb] = fmaf(h0.w, whh[k0+3], accA[nb]);
                    accB[nb] = fmaf(h1.x, whh[k0+4], accB[nb]);
                    accB[nb] = fmaf(h1.y, whh[k0+5], accB[nb]);
                    accB[nb] = fmaf(h1.z, whh[k0+6], accB[nb]);
                    accB[nb] = fmaf(h1.w, whh[k0+7], accB[nb]);
                }
            }
        }
        #pragma unroll
        for (int nb = 0; nb < NB; ++nb) pre[nb][t] = accA[nb] + accB[nb];
        __syncthreads();

        // ---------- Phase B: activations for (batch w, unit u) + fused e2 ----------
        {
            float pi = pre[w][u], pf = pre[w][64 + u], pg = pre[w][128 + u], po = pre[w][192 + u];
            float si = sigm(pi), sf = sigm(pf), tg = tanh_(pg), so = sigm(po);
            c_reg = fmaf(sf, c_reg, si * tg);
            float h = so * tanh_(c_reg);
            h_s[w][u] = h;
            // e2 gate-preact: wave w handles batch w; lane (g,part) -> 4-elem slice
            float4 hv = *(const float4*)&h_s[w][part * 4];   // wave-sync RAW, lgkmcnt
            float s = fmaf(hv.x, e2w0, fmaf(hv.y, e2w1, fmaf(hv.z, e2w2, hv.w * e2w3)));
            s += __shfl_xor(s, 1); s += __shfl_xor(s, 2);
            s += __shfl_xor(s, 4); s += __shfl_xor(s, 8);
            if (part == 0)
                pe2[((size_t)ts * 4096 + b0 + w) * 4 + g] = s + e2bias;
        }
        __syncthreads();
    }
}

// ============ K2: e2 recurrence (H=1), lane = batch; build dec_in ============
__global__ void k2_e2(const float* __restrict__ pe2, const float* __restrict__ e2_Whh,
                      const float* __restrict__ x, float* __restrict__ dec_in)
{
    const int b = blockIdx.x * 256 + threadIdx.x;
    const float w0 = e2_Whh[0], w1 = e2_Whh[1], w2 = e2_Whh[2], w3 = e2_Whh[3];
    const float4* pp = (const float4*)pe2;
    float h = 0.f, c = 0.f;
    for (int ts = 0; ts < 96; ++ts) {
        float4 g4 = pp[(size_t)ts * 4096 + b];
        float gi = fmaf(h, w0, g4.x);
        float gf = fmaf(h, w1, g4.y);
        float gg = fmaf(h, w2, g4.z);
        float go = fmaf(h, w3, g4.w);
        c = fmaf(sigm(gf), c, sigm(gi) * tanh_(gg));
        h = sigm(go) * tanh_(c);
        dec_in[(size_t)b * 128 + ts] = fmaxf(h, 0.f);
    }
    #pragma unroll 4
    for (int j = 0; j < 32; ++j)
        dec_in[(size_t)b * 128 + 96 + j] = x[(size_t)b * 768 + (64 + j) * 8];
}

// ============ K3: d1 LSTM(1->16) 128 steps, 4 batches/wave + fused d2-xg ============
__global__ __launch_bounds__(256, 2) void k3_d1(
    const float* __restrict__ dec_in,
    const float* __restrict__ d1_Wih, const float* __restrict__ d1_Whh, const float* __restrict__ d1_b,
    const float* __restrict__ d2_Wih, const float* __restrict__ d2_b,
    float* __restrict__ pd2)   // [ts][4096][4]
{
    __shared__ float din_s[16 * 128];
    __shared__ float h_lds[16][16];

    const int t = threadIdx.x;
    const int w = t >> 6, lane = t & 63;
    const int q = lane >> 4, u = lane & 15;
    const int row = w * 4 + q;
    const size_t b = (size_t)blockIdx.x * 16 + row;

    for (int i = t; i < 2048; i += 256) din_s[i] = dec_in[(size_t)blockIdx.x * 2048 + i];

    float wih_g[4], bg[4], whh_g[4][16], d2w[16];
    #pragma unroll
    for (int g = 0; g < 4; ++g) {
        wih_g[g] = d1_Wih[g * 16 + u];
        bg[g]    = d1_b[g * 16 + u];
        const float4* wp = (const float4*)(d1_Whh + (size_t)(g * 16 + u) * 16);
        #pragma unroll
        for (int qq = 0; qq < 4; ++qq) {
            float4 v = wp[qq];
            whh_g[g][4*qq+0] = v.x; whh_g[g][4*qq+1] = v.y;
            whh_g[g][4*qq+2] = v.z; whh_g[g][4*qq+3] = v.w;
        }
    }
    {
        const float4* wp = (const float4*)(d2_Wih + (size_t)(u & 3) * 16);
        #pragma unroll
        for (int qq = 0; qq < 4; ++qq) {
            float4 v = wp[qq];
            d2w[4*qq+0] = v.x; d2w[4*qq+1] = v.y; d2w[4*qq+2] = v.z; d2w[4*qq+3] = v.w;
        }
    }
    const float d2bias = d2_b[u & 3];

    float h = 0.f, c = 0.f;
    __syncthreads();

    float hv[16];
    for (int ts = 0; ts < 128; ++ts) {
        float xv = din_s[row * 128 + ts];
        float p0 = fmaf(xv, wih_g[0], bg[0]);
        float p1 = fmaf(xv, wih_g[1], bg[1]);
        float p2 = fmaf(xv, wih_g[2], bg[2]);
        float p3 = fmaf(xv, wih_g[3], bg[3]);
        if (ts > 0) {
            const float4* hp = (const float4*)&h_lds[row][0];
            #pragma unroll
            for (int qq = 0; qq < 4; ++qq) {
                float4 v = hp[qq];
                hv[4*qq+0] = v.x; hv[4*qq+1] = v.y; hv[4*qq+2] = v.z; hv[4*qq+3] = v.w;
            }
            #pragma unroll
            for (int k = 0; k < 16; ++k) {
                p0 = fmaf(hv[k], whh_g[0][k], p0);
                p1 = fmaf(hv[k], whh_g[1][k], p1);
                p2 = fmaf(hv[k], whh_g[2][k], p2);
                p3 = fmaf(hv[k], whh_g[3][k], p3);
            }
            if (u < 4) {
                float a = d2bias;
                #pragma unroll
                for (int k = 0; k < 16; ++k) a = fmaf(hv[k], d2w[k], a);
                pd2[((size_t)(ts - 1) * 4096 + b) * 4 + u] = a;
            }
        }
        c = fmaf(sigm(p1), c, sigm(p0) * tanh_(p2));
        h = sigm(p3) * tanh_(c);
        h_lds[row][u] = h;
    }
    {
        const float4* hp = (const float4*)&h_lds[row][0];
        #pragma unroll
        for (int qq = 0; qq < 4; ++qq) {
            float4 v = hp[qq];
            hv[4*qq+0] = v.x; hv[4*qq+1] = v.y; hv[4*qq+2] = v.z; hv[4*qq+3] = v.w;
        }
        if (u < 4) {
            float a = d2bias;
            #pragma unroll
            for (int k = 0; k < 16; ++k) a = fmaf(hv[k], d2w[k], a);
            pd2[((size_t)127 * 4096 + b) * 4 + u] = a;
        }
    }
}

// ============ K5: d2 recurrence (H=1), lane = batch ============
__global__ void k5_d2(const float* __restrict__ pd2, const float* __restrict__ d2_Whh,
                      float* __restrict__ d2h)   // [ts][4096]
{
    const int b = blockIdx.x * 256 + threadIdx.x;
    const float w0 = d2_Whh[0], w1 = d2_Whh[1], w2 = d2_Whh[2], w3 = d2_Whh[3];
    const float4* pp = (const float4*)pd2;
    float h = 0.f, c = 0.f;
    for (int ts = 0; ts < 128; ++ts) {
        float4 g4 = pp[(size_t)ts * 4096 + b];
        float gi = fmaf(h, w0, g4.x);
        float gf = fmaf(h, w1, g4.y);
        float gg = fmaf(h, w2, g4.z);
        float go = fmaf(h, w3, g4.w);
        c = fmaf(sigm(gf), c, sigm(gi) * tanh_(gg));
        h = sigm(go) * tanh_(c);
        d2h[(size_t)ts * 4096 + b] = h;
    }
}

// ============ K6: fc1(128->32) + fc2(32->32), 8 batches/block ============
__global__ __launch_bounds__(256) void k6_fc(
    const float* __restrict__ d2h,
    const float* __restrict__ fc1_W, const float* __restrict__ fc1_b,
    const float* __restrict__ fc2_W, const float* __restrict__ fc2_b,
    float* __restrict__ out)
{
    __shared__ float flat_s[8][128];
    __shared__ float mid_s[8][32];
    const int t = threadIdx.x;
    const int s = t >> 5, o = t & 31;
    const size_t b0 = (size_t)blockIdx.x * 8;

    for (int i = t; i < 1024; i += 256) {
        int ts = i >> 3, ss = i & 7;
        flat_s[ss][ts] = d2h[(size_t)ts * 4096 + b0 + ss];
    }
    __syncthreads();

    float a = fc1_b[o];
    {
        const float4* wp = (const float4*)(fc1_W + (size_t)o * 128);
        const float4* fp = (const float4*)flat_s[s];
        #pragma unroll
        for (int qq = 0; qq < 32; ++qq) {
            float4 f = fp[qq], wv = wp[qq];
            a = fmaf(f.x, wv.x, a); a = fmaf(f.y, wv.y, a);
            a = fmaf(f.z, wv.z, a); a = fmaf(f.w, wv.w, a);
        }
    }
    mid_s[s][o] = a;
    __syncthreads();

    float a2 = fc2_b[o];
    {
        const float4* wp = (const float4*)(fc2_W + (size_t)o * 32);
        const float4* mp = (const float4*)mid_s[s];
        #pragma unroll
        for (int qq = 0; qq < 8; ++qq) {
            float4 m = mp[qq], wv = wp[qq];
            a2 = fmaf(m.x, wv.x, a2); a2 = fmaf(m.y, wv.y, a2);
            a2 = fmaf(m.z, wv.z, a2); a2 = fmaf(m.w, wv.w, a2);
        }
    }
    out[(b0 + s) * 32 + o] = a2;
}

extern "C" void kernel_launch(void* const* d_in, const int* in_sizes, int n_in,
                              void* d_out, int out_size, void* d_ws, size_t ws_size,
                              hipStream_t stream) {
    const float* x      = (const float*)d_in[0];
    const float* e1_Wih = (const float*)d_in[1];
    const float* e1_Whh = (const float*)d_in[2];
    const float* e1_b   = (const float*)d_in[3];
    const float* e2_Wih = (const float*)d_in[4];
    const float* e2_Whh = (const float*)d_in[5];
    const float* e2_b   = (const float*)d_in[6];
    const float* d1_Wih = (const float*)d_in[7];
    const float* d1_Whh = (const float*)d_in[8];
    const float* d1_b   = (const float*)d_in[9];
    const float* d2_Wih = (const float*)d_in[10];
    const float* d2_Whh = (const float*)d_in[11];
    const float* d2_b   = (const float*)d_in[12];
    const float* fc1_W  = (const float*)d_in[13];
    const float* fc1_b  = (const float*)d_in[14];
    const float* fc2_W  = (const float*)d_in[15];
    const float* fc2_b  = (const float*)d_in[16];
    float* out = (float*)d_out;

    float* ws     = (float*)d_ws;
    float* pe2    = ws;                 // [96][4096][4]; reused as pd2 [128][4096][4]
    float* dec_in = ws + 2097152;       // [4096][128]
    float* d2h    = ws + 2621440;       // [128][4096]

    hipLaunchKernelGGL(k1_e1, dim3(1024), dim3(256), 0, stream,
                       x, e1_Wih, e1_Whh, e1_b, e2_Wih, e2_b, pe2);
    hipLaunchKernelGGL(k2_e2, dim3(16), dim3(256), 0, stream, pe2, e2_Whh, x, dec_in);
    hipLaunchKernelGGL(k3_d1, dim3(256), dim3(256), 0, stream,
                       dec_in, d1_Wih, d1_Whh, d1_b, d2_Wih, d2_b, pe2 /*pd2*/);
    hipLaunchKernelGGL(k5_d2, dim3(16), dim3(256), 0, stream, pe2 /*pd2*/, d2_Whh, d2h);
    hipLaunchKernelGGL(k6_fc, dim3(512), dim3(256), 0, stream,
                       d2h, fc1_W, fc1_b, fc2_W, fc2_b, out);
}